// Round 5
// baseline (206.162 us; speedup 1.0000x reference)
//
#include <hip/hip_runtime.h>
#include <hip/hip_bf16.h>

// Problem constants (B=1 folded out)
constexpr int T = 8;     // frames
constexpr int C = 128;   // input channels
constexpr int N = 4096;  // H*W positions
constexpr int F = 64;    // feature dim

typedef __bf16 bf16x8 __attribute__((ext_vector_type(8)));
typedef __bf16 bf16x4 __attribute__((ext_vector_type(4)));
typedef float  f32x4  __attribute__((ext_vector_type(4)));
typedef float  f32x16 __attribute__((ext_vector_type(16)));

// ---------------------------------------------------------------------------
// Kernel 1: projections, LDS-free (unchanged from R4 — known correct).
//   Q = x1ᵀW1ᵀ+b1  -> bf16 [t][n][F]
//   K = x2ᵀW2ᵀ+b2  -> bf16 [t][n][F]
//   G = x1ᵀW3ᵀ+b3  -> bf16 [t][f][N]
// Also zeroes d_out (poisoned 0xAA; attn accumulates atomically).
// ---------------------------------------------------------------------------
__global__ __launch_bounds__(256) void proj_kernel(
    const float* __restrict__ x1, const float* __restrict__ x2,
    const float* __restrict__ W1, const float* __restrict__ b1,
    const float* __restrict__ W2, const float* __restrict__ b2,
    const float* __restrict__ W3, const float* __restrict__ b3,
    __bf16* __restrict__ Qb, __bf16* __restrict__ Kb, __bf16* __restrict__ Gw,
    float* __restrict__ out)
{
    const int t   = blockIdx.x >> 6;    // 64 blocks per t, 64 npos per block
    const int nb  = blockIdx.x & 63;
    const int tid = threadIdx.x, wave = tid >> 6, lane = tid & 63;
    const int quad = lane >> 4, l16 = lane & 15;
    const int nw = nb * 64 + wave * 16;          // this wave's 16 positions

    // zero this block's 4096-float slice of d_out (512 blocks cover T*F*N)
    {
        f32x4* o4 = (f32x4*)out + (size_t)blockIdx.x * 1024;
#pragma unroll
        for (int i = 0; i < 4; ++i) o4[i * 256 + tid] = (f32x4){0.f, 0.f, 0.f, 0.f};
    }

    // x B-frags: B[k=c][n'=npos]; lane n'=l16, k = cc*32 + quad*8 + j
    bf16x8 xf1[4], xf2[4];
#pragma unroll
    for (int cc = 0; cc < 4; ++cc) {
#pragma unroll
        for (int j = 0; j < 8; ++j) {
            size_t off = ((size_t)t * C + cc * 32 + quad * 8 + j) * (size_t)N + nw + l16;
            xf1[cc][j] = (__bf16)x1[off];
            xf2[cc][j] = (__bf16)x2[off];
        }
    }

    const float* Ws[3] = {W1, W2, W3};
    const float* bs[3] = {b1, b2, b3};

#pragma unroll
    for (int p = 0; p < 3; ++p) {
        const float* W    = Ws[p];
        const float* bias = bs[p];
#pragma unroll
        for (int fb = 0; fb < 4; ++fb) {
            f32x4 acc = (f32x4){0.f, 0.f, 0.f, 0.f};
#pragma unroll
            for (int cc = 0; cc < 4; ++cc) {
                const f32x4* wp = (const f32x4*)&W[(fb * 16 + l16) * C + cc * 32 + quad * 8];
                f32x4 w0 = wp[0], w1 = wp[1];
                bf16x8 wf;
                wf[0] = (__bf16)w0[0]; wf[1] = (__bf16)w0[1];
                wf[2] = (__bf16)w0[2]; wf[3] = (__bf16)w0[3];
                wf[4] = (__bf16)w1[0]; wf[5] = (__bf16)w1[1];
                wf[6] = (__bf16)w1[2]; wf[7] = (__bf16)w1[3];
                bf16x8 xb = (p == 1) ? xf2[cc] : xf1[cc];
                acc = __builtin_amdgcn_mfma_f32_16x16x32_bf16(wf, xb, acc, 0, 0, 0);
            }
            if (p < 2) {
                __bf16* O = p ? Kb : Qb;
                bf16x4 ov;
#pragma unroll
                for (int r = 0; r < 4; ++r)
                    ov[r] = (__bf16)(acc[r] + bias[fb * 16 + quad * 4 + r]);
                *(bf16x4*)&O[((size_t)t * N + nw + l16) * F + fb * 16 + quad * 4] = ov;
            } else {
#pragma unroll
                for (int r = 0; r < 4; ++r) {
                    int f = fb * 16 + quad * 4 + r;
                    Gw[((size_t)t * F + f) * (size_t)N + nw + l16] = (__bf16)(acc[r] + bias[f]);
                }
            }
        }
    }
}

// ---------------------------------------------------------------------------
// pack two relu'd fp32 into a bf16x2 dword
// ---------------------------------------------------------------------------
__device__ inline unsigned pk_relu(float a, float b) {
    union { __bf16 h[2]; unsigned u; } x;
    x.h[0] = (__bf16)fmaxf(a, 0.f);
    x.h[1] = (__bf16)fmaxf(b, 0.f);
    return x.u;
}

// ---------------------------------------------------------------------------
// Kernel 2: O[t][f][q] += sum_key relu(Q[q]·K[key]) * G[key][f]
// mfma_f32_32x32x16_bf16 throughout. NO LDS, NO barriers:
//  - K/G fragments read directly from global (identical across the block's
//    4 waves and reused across q-blocks -> L1/L2-resident).
//  - S exits the QK-GEMM in C-layout (col=q=lane&31, row=key=(r&3)+8(r>>2)+4h)
//    and is converted in-register to the PV B-operand layout (k=(h*8+j)) via
//    a lane-xor-32 exchange of half the packed dwords (4 shfl per subtile).
// Wave owns 64 q (2 subtiles of 32); block 256 thr = 256 q. KSPLIT=4 over
// keys; fp32 atomic accumulate into out[t][f][n].
// ---------------------------------------------------------------------------
constexpr int KSPLIT = 4;

__global__ __launch_bounds__(256) void attn_kernel(
    const __bf16* __restrict__ Qb, const __bf16* __restrict__ Kb,
    const __bf16* __restrict__ Gw, float* __restrict__ out)
{
    const int ks = blockIdx.x & (KSPLIT - 1);
    const int qb = (blockIdx.x / KSPLIT) & 15;   // N/256 = 16 q-blocks
    const int t  = blockIdx.x / (KSPLIT * 16);

    const int tid = threadIdx.x, wave = tid >> 6, lane = tid & 63;
    const int l32 = lane & 31, h = lane >> 5;
    const int qw = qb * 256 + wave * 64;         // this wave's 64 queries

    const __bf16* Kbase = Kb + (size_t)t * N * F;
    const __bf16* Gbase = Gw + (size_t)t * F * N;

    // persistent Q B-frags: B[n=q][k=f]; q = qw + qt*32 + l32, f = c*16 + h*8 + j
    bf16x8 qf[2][4];
#pragma unroll
    for (int qt = 0; qt < 2; ++qt)
#pragma unroll
        for (int c = 0; c < 4; ++c)
            qf[qt][c] = *(const bf16x8*)&Qb[((size_t)t * N + qw + qt * 32 + l32) * F + c * 16 + h * 8];

    f32x16 oacc[2][2];   // [ft][qt], Oᵀ subtiles: col=q, row=f
#pragma unroll
    for (int ft = 0; ft < 2; ++ft)
#pragma unroll
        for (int qt = 0; qt < 2; ++qt)
#pragma unroll
            for (int i = 0; i < 16; ++i) oacc[ft][qt][i] = 0.f;

    const int kb_lo = ks * (N / 64 / KSPLIT);
    const int kb_hi = kb_lo + (N / 64 / KSPLIT);

    for (int kb = kb_lo; kb < kb_hi; ++kb) {
        const int k0 = kb * 64;
        bf16x8 sfrag[2][4];   // [qt][kc], PV B-frags for this 64-key tile

#pragma unroll
        for (int kt = 0; kt < 2; ++kt) {
            // S-GEMM: Sᵀ[key32][q32] per qt; A = K-frag (m=key, k=f)
            f32x16 sd[2];
#pragma unroll
            for (int qt = 0; qt < 2; ++qt)
#pragma unroll
                for (int i = 0; i < 16; ++i) sd[qt][i] = 0.f;
#pragma unroll
            for (int c = 0; c < 4; ++c) {
                bf16x8 kf = *(const bf16x8*)&Kbase[(size_t)(k0 + kt * 32 + l32) * F + c * 16 + h * 8];
                sd[0] = __builtin_amdgcn_mfma_f32_32x32x16_bf16(kf, qf[0][c], sd[0], 0, 0, 0);
                sd[1] = __builtin_amdgcn_mfma_f32_32x32x16_bf16(kf, qf[1][c], sd[1], 0, 0, 0);
            }
            // relu + pack + lane-xor-32 transform: C-layout -> B-operand layout
#pragma unroll
            for (int qt = 0; qt < 2; ++qt) {
                unsigned p0 = pk_relu(sd[qt][0],  sd[qt][1]);
                unsigned p1 = pk_relu(sd[qt][2],  sd[qt][3]);
                unsigned p2 = pk_relu(sd[qt][4],  sd[qt][5]);
                unsigned p3 = pk_relu(sd[qt][6],  sd[qt][7]);
                unsigned p4 = pk_relu(sd[qt][8],  sd[qt][9]);
                unsigned p5 = pk_relu(sd[qt][10], sd[qt][11]);
                unsigned p6 = pk_relu(sd[qt][12], sd[qt][13]);
                unsigned p7 = pk_relu(sd[qt][14], sd[qt][15]);
                // each lane sends what its xor-32 partner needs
                unsigned r0 = (unsigned)__shfl_xor((int)(h ? p0 : p2), 32, 64);
                unsigned r1 = (unsigned)__shfl_xor((int)(h ? p1 : p3), 32, 64);
                unsigned r2 = (unsigned)__shfl_xor((int)(h ? p4 : p6), 32, 64);
                unsigned r3 = (unsigned)__shfl_xor((int)(h ? p5 : p7), 32, 64);
                union { unsigned u[4]; bf16x8 v; } f0, f1;
                f0.u[0] = h ? r0 : p0;  f0.u[1] = h ? r1 : p1;
                f0.u[2] = h ? p2 : r0;  f0.u[3] = h ? p3 : r1;
                f1.u[0] = h ? r2 : p4;  f1.u[1] = h ? r3 : p5;
                f1.u[2] = h ? p6 : r2;  f1.u[3] = h ? p7 : r3;
                sfrag[qt][kt * 2 + 0] = f0.v;
                sfrag[qt][kt * 2 + 1] = f1.v;
            }
        }

        // PV: Oᵀ[f][q] += G-frag(m=f,k=key) x S-frag(k=key,n=q)
#pragma unroll
        for (int ft = 0; ft < 2; ++ft) {
#pragma unroll
            for (int kc = 0; kc < 4; ++kc) {
                bf16x8 gf = *(const bf16x8*)&Gbase[(size_t)(ft * 32 + l32) * N + k0 + kc * 16 + h * 8];
                oacc[ft][0] = __builtin_amdgcn_mfma_f32_32x32x16_bf16(gf, sfrag[0][kc], oacc[ft][0], 0, 0, 0);
                oacc[ft][1] = __builtin_amdgcn_mfma_f32_32x32x16_bf16(gf, sfrag[1][kc], oacc[ft][1], 0, 0, 0);
            }
        }
    }

    // Epilogue: D col = q = l32, row = f_local = (r&3) + 8*(r>>2) + 4*h
#pragma unroll
    for (int ft = 0; ft < 2; ++ft)
#pragma unroll
        for (int qt = 0; qt < 2; ++qt)
#pragma unroll
            for (int r = 0; r < 16; ++r) {
                int f = ft * 32 + (r & 3) + 8 * (r >> 2) + 4 * h;
                int q = qw + qt * 32 + l32;
                unsafeAtomicAdd(&out[((size_t)t * F + f) * (size_t)N + q], oacc[ft][qt][r]);
            }
}

// ---------------------------------------------------------------------------
extern "C" void kernel_launch(void* const* d_in, const int* in_sizes, int n_in,
                              void* d_out, int out_size, void* d_ws, size_t ws_size,
                              hipStream_t stream) {
    const float* x1 = (const float*)d_in[0];
    const float* x2 = (const float*)d_in[1];
    const float* W1 = (const float*)d_in[2];
    const float* b1 = (const float*)d_in[3];
    const float* W2 = (const float*)d_in[4];
    const float* b2 = (const float*)d_in[5];
    const float* W3 = (const float*)d_in[6];
    const float* b3 = (const float*)d_in[7];
    float* out = (float*)d_out;

    // workspace: Q [t][n][F], K [t][n][F], G [t][f][N] bf16 (3 x 4 MiB)
    __bf16* Qb = (__bf16*)d_ws;
    __bf16* Kb = Qb + (size_t)T * N * F;
    __bf16* Gw = Kb + (size_t)T * N * F;

    proj_kernel<<<dim3(T * (N / 64)), dim3(256), 0, stream>>>(
        x1, x2, W1, b1, W2, b2, W3, b3, Qb, Kb, Gw, out);
    attn_kernel<<<dim3(T * 16 * KSPLIT), dim3(256), 0, stream>>>(Qb, Kb, Gw, out);
}

// Round 6
// 183.383 us; speedup vs baseline: 1.1242x; 1.1242x over previous
//
#include <hip/hip_runtime.h>
#include <hip/hip_bf16.h>

// Problem constants (B=1 folded out)
constexpr int T = 8;     // frames
constexpr int C = 128;   // input channels
constexpr int N = 4096;  // H*W positions
constexpr int F = 64;    // feature dim

typedef __bf16 bf16x8 __attribute__((ext_vector_type(8)));
typedef __bf16 bf16x4 __attribute__((ext_vector_type(4)));
typedef float  f32x4  __attribute__((ext_vector_type(4)));
typedef float  f32x16 __attribute__((ext_vector_type(16)));

// ---------------------------------------------------------------------------
// Kernel 1: projections, LDS-free (unchanged — known correct).
//   Q = x1ᵀW1ᵀ+b1  -> bf16 [t][n][F]
//   K = x2ᵀW2ᵀ+b2  -> bf16 [t][n][F]
//   G = x1ᵀW3ᵀ+b3  -> bf16 [t][f][N]
// Also zeroes d_out (poisoned 0xAA; attn accumulates atomically).
// ---------------------------------------------------------------------------
__global__ __launch_bounds__(256) void proj_kernel(
    const float* __restrict__ x1, const float* __restrict__ x2,
    const float* __restrict__ W1, const float* __restrict__ b1,
    const float* __restrict__ W2, const float* __restrict__ b2,
    const float* __restrict__ W3, const float* __restrict__ b3,
    __bf16* __restrict__ Qb, __bf16* __restrict__ Kb, __bf16* __restrict__ Gw,
    float* __restrict__ out)
{
    const int t   = blockIdx.x >> 6;    // 64 blocks per t, 64 npos per block
    const int nb  = blockIdx.x & 63;
    const int tid = threadIdx.x, wave = tid >> 6, lane = tid & 63;
    const int quad = lane >> 4, l16 = lane & 15;
    const int nw = nb * 64 + wave * 16;          // this wave's 16 positions

    // zero this block's 4096-float slice of d_out (512 blocks cover T*F*N)
    {
        f32x4* o4 = (f32x4*)out + (size_t)blockIdx.x * 1024;
#pragma unroll
        for (int i = 0; i < 4; ++i) o4[i * 256 + tid] = (f32x4){0.f, 0.f, 0.f, 0.f};
    }

    // x B-frags: B[k=c][n'=npos]; lane n'=l16, k = cc*32 + quad*8 + j
    bf16x8 xf1[4], xf2[4];
#pragma unroll
    for (int cc = 0; cc < 4; ++cc) {
#pragma unroll
        for (int j = 0; j < 8; ++j) {
            size_t off = ((size_t)t * C + cc * 32 + quad * 8 + j) * (size_t)N + nw + l16;
            xf1[cc][j] = (__bf16)x1[off];
            xf2[cc][j] = (__bf16)x2[off];
        }
    }

    const float* Ws[3] = {W1, W2, W3};
    const float* bs[3] = {b1, b2, b3};

#pragma unroll
    for (int p = 0; p < 3; ++p) {
        const float* W    = Ws[p];
        const float* bias = bs[p];
#pragma unroll
        for (int fb = 0; fb < 4; ++fb) {
            f32x4 acc = (f32x4){0.f, 0.f, 0.f, 0.f};
#pragma unroll
            for (int cc = 0; cc < 4; ++cc) {
                const f32x4* wp = (const f32x4*)&W[(fb * 16 + l16) * C + cc * 32 + quad * 8];
                f32x4 w0 = wp[0], w1 = wp[1];
                bf16x8 wf;
                wf[0] = (__bf16)w0[0]; wf[1] = (__bf16)w0[1];
                wf[2] = (__bf16)w0[2]; wf[3] = (__bf16)w0[3];
                wf[4] = (__bf16)w1[0]; wf[5] = (__bf16)w1[1];
                wf[6] = (__bf16)w1[2]; wf[7] = (__bf16)w1[3];
                bf16x8 xb = (p == 1) ? xf2[cc] : xf1[cc];
                acc = __builtin_amdgcn_mfma_f32_16x16x32_bf16(wf, xb, acc, 0, 0, 0);
            }
            if (p < 2) {
                __bf16* O = p ? Kb : Qb;
                bf16x4 ov;
#pragma unroll
                for (int r = 0; r < 4; ++r)
                    ov[r] = (__bf16)(acc[r] + bias[fb * 16 + quad * 4 + r]);
                *(bf16x4*)&O[((size_t)t * N + nw + l16) * F + fb * 16 + quad * 4] = ov;
            } else {
#pragma unroll
                for (int r = 0; r < 4; ++r) {
                    int f = fb * 16 + quad * 4 + r;
                    Gw[((size_t)t * F + f) * (size_t)N + nw + l16] = (__bf16)(acc[r] + bias[f]);
                }
            }
        }
    }
}

// ---------------------------------------------------------------------------
// pack two relu'd fp32 into a bf16x2 dword
// ---------------------------------------------------------------------------
__device__ inline unsigned pk_relu(float a, float b) {
    union { __bf16 h[2]; unsigned u; } x;
    x.h[0] = (__bf16)fmaxf(a, 0.f);
    x.h[1] = (__bf16)fmaxf(b, 0.f);
    return x.u;
}

// ---------------------------------------------------------------------------
// Kernel 2: O[t][f][q] += sum_key relu(Q[q]·K[key]) * G[key][f]
// mfma_f32_32x32x16_bf16 throughout (R5-proven layouts).
//  - K/G tiles staged in LDS with an XOR-swizzled 16B-chunk layout
//    (chunk ^= row&7): staging writes and frag reads conflict-free; 16 KB.
//  - Register prefetch of next tile overlaps global latency with compute.
//  - S converted C-layout -> PV B-operand layout in-register via lane-xor-32
//    dword exchange (R5-proven, no Sb array).
// Wave owns 64 q (2 subtiles of 32); block 256 thr = 256 q. KSPLIT=8 over
// keys; fp32 atomic accumulate into out[t][f][n].
// ---------------------------------------------------------------------------
constexpr int KSPLIT = 8;

__global__ __launch_bounds__(256) void attn_kernel(
    const __bf16* __restrict__ Qb, const __bf16* __restrict__ Kb,
    const __bf16* __restrict__ Gw, float* __restrict__ out)
{
    const int ks = blockIdx.x & (KSPLIT - 1);
    const int qb = (blockIdx.x / KSPLIT) & 15;   // N/256 = 16 q-blocks
    const int t  = blockIdx.x / (KSPLIT * 16);

    __shared__ __bf16 Kt[64 * 64];   // [key][f], 16B chunks XOR-swizzled (8 KB)
    __shared__ __bf16 Gt[64 * 64];   // [f][key], same swizzle            (8 KB)

    const int tid = threadIdx.x, wave = tid >> 6, lane = tid & 63;
    const int l32 = lane & 31, h = lane >> 5;
    const int qw = qb * 256 + wave * 64;         // this wave's 64 queries

    const __bf16* Kbase = Kb + (size_t)t * N * F;
    const __bf16* Gbase = Gw + (size_t)t * F * N;

    // persistent Q B-frags: B[n=q][k=f]; q = qw + qt*32 + l32, f = c*16 + h*8 + j
    bf16x8 qf[2][4];
#pragma unroll
    for (int qt = 0; qt < 2; ++qt)
#pragma unroll
        for (int c = 0; c < 4; ++c)
            qf[qt][c] = *(const bf16x8*)&Qb[((size_t)t * N + qw + qt * 32 + l32) * F + c * 16 + h * 8];

    f32x16 oacc[2][2];   // [ft][qt], Oᵀ subtiles: col=q, row=f
#pragma unroll
    for (int ft = 0; ft < 2; ++ft)
#pragma unroll
        for (int qt = 0; qt < 2; ++qt)
#pragma unroll
            for (int i = 0; i < 16; ++i) oacc[ft][qt][i] = 0.f;

    const int kb_lo = ks * (N / 64 / KSPLIT);
    const int kb_hi = kb_lo + (N / 64 / KSPLIT);

    // staging: 2 units/thread; unit u -> row u>>3 (0..63), chunk u&7
    const int ra = tid >> 3, ca = tid & 7;       // rows 0..31
    const int rb = ra + 32,  cb = ca;            // rows 32..63
    const int wKa = ra * 64 + ((ca ^ (ra & 7)) * 8);
    const int wKb = rb * 64 + ((cb ^ (rb & 7)) * 8);

    bf16x8 kv0, kv1, gv0, gv1;
    {
        const int k0 = kb_lo * 64;
        kv0 = *(const bf16x8*)&Kbase[(size_t)(k0 + ra) * F + ca * 8];
        kv1 = *(const bf16x8*)&Kbase[(size_t)(k0 + rb) * F + cb * 8];
        gv0 = *(const bf16x8*)&Gbase[(size_t)ra * N + k0 + ca * 8];
        gv1 = *(const bf16x8*)&Gbase[(size_t)rb * N + k0 + cb * 8];
    }

    for (int kb = kb_lo; kb < kb_hi; ++kb) {
        __syncthreads();   // previous tile's LDS reads done
        *(bf16x8*)&Kt[wKa] = kv0;
        *(bf16x8*)&Kt[wKb] = kv1;
        *(bf16x8*)&Gt[wKa] = gv0;
        *(bf16x8*)&Gt[wKb] = gv1;
        __syncthreads();

        if (kb + 1 < kb_hi) {   // prefetch next tile (overlaps compute)
            const int k0 = (kb + 1) * 64;
            kv0 = *(const bf16x8*)&Kbase[(size_t)(k0 + ra) * F + ca * 8];
            kv1 = *(const bf16x8*)&Kbase[(size_t)(k0 + rb) * F + cb * 8];
            gv0 = *(const bf16x8*)&Gbase[(size_t)ra * N + k0 + ca * 8];
            gv1 = *(const bf16x8*)&Gbase[(size_t)rb * N + k0 + cb * 8];
        }

        bf16x8 sfrag[2][4];   // [qt][kc], PV B-frags for this 64-key tile

#pragma unroll
        for (int kt = 0; kt < 2; ++kt) {
            // S-GEMM: Sᵀ[key32][q32] per qt; A = K-frag (m=key, k=f)
            f32x16 sd[2];
#pragma unroll
            for (int qt = 0; qt < 2; ++qt)
#pragma unroll
                for (int i = 0; i < 16; ++i) sd[qt][i] = 0.f;
#pragma unroll
            for (int c = 0; c < 4; ++c) {
                int row = kt * 32 + l32;
                bf16x8 kf = *(const bf16x8*)&Kt[row * 64 + (((2 * c + h) ^ (row & 7)) * 8)];
                sd[0] = __builtin_amdgcn_mfma_f32_32x32x16_bf16(kf, qf[0][c], sd[0], 0, 0, 0);
                sd[1] = __builtin_amdgcn_mfma_f32_32x32x16_bf16(kf, qf[1][c], sd[1], 0, 0, 0);
            }
            // relu + pack + lane-xor-32 transform: C-layout -> B-operand layout
#pragma unroll
            for (int qt = 0; qt < 2; ++qt) {
                unsigned p0 = pk_relu(sd[qt][0],  sd[qt][1]);
                unsigned p1 = pk_relu(sd[qt][2],  sd[qt][3]);
                unsigned p2 = pk_relu(sd[qt][4],  sd[qt][5]);
                unsigned p3 = pk_relu(sd[qt][6],  sd[qt][7]);
                unsigned p4 = pk_relu(sd[qt][8],  sd[qt][9]);
                unsigned p5 = pk_relu(sd[qt][10], sd[qt][11]);
                unsigned p6 = pk_relu(sd[qt][12], sd[qt][13]);
                unsigned p7 = pk_relu(sd[qt][14], sd[qt][15]);
                // each lane sends what its xor-32 partner needs
                unsigned r0 = (unsigned)__shfl_xor((int)(h ? p0 : p2), 32, 64);
                unsigned r1 = (unsigned)__shfl_xor((int)(h ? p1 : p3), 32, 64);
                unsigned r2 = (unsigned)__shfl_xor((int)(h ? p4 : p6), 32, 64);
                unsigned r3 = (unsigned)__shfl_xor((int)(h ? p5 : p7), 32, 64);
                union { unsigned u[4]; bf16x8 v; } f0, f1;
                f0.u[0] = h ? r0 : p0;  f0.u[1] = h ? r1 : p1;
                f0.u[2] = h ? p2 : r0;  f0.u[3] = h ? p3 : r1;
                f1.u[0] = h ? r2 : p4;  f1.u[1] = h ? r3 : p5;
                f1.u[2] = h ? p6 : r2;  f1.u[3] = h ? p7 : r3;
                sfrag[qt][kt * 2 + 0] = f0.v;
                sfrag[qt][kt * 2 + 1] = f1.v;
            }
        }

        // PV: Oᵀ[f][q] += G-frag(m=f,k=key) x S-frag(k=key,n=q)
#pragma unroll
        for (int ft = 0; ft < 2; ++ft) {
#pragma unroll
            for (int kc = 0; kc < 4; ++kc) {
                int row = ft * 32 + l32;
                bf16x8 gf = *(const bf16x8*)&Gt[row * 64 + (((2 * kc + h) ^ (row & 7)) * 8)];
                oacc[ft][0] = __builtin_amdgcn_mfma_f32_32x32x16_bf16(gf, sfrag[0][kc], oacc[ft][0], 0, 0, 0);
                oacc[ft][1] = __builtin_amdgcn_mfma_f32_32x32x16_bf16(gf, sfrag[1][kc], oacc[ft][1], 0, 0, 0);
            }
        }
    }

    // Epilogue: D col = q = l32, row = f_local = (r&3) + 8*(r>>2) + 4*h
#pragma unroll
    for (int ft = 0; ft < 2; ++ft)
#pragma unroll
        for (int qt = 0; qt < 2; ++qt)
#pragma unroll
            for (int r = 0; r < 16; ++r) {
                int f = ft * 32 + (r & 3) + 8 * (r >> 2) + 4 * h;
                int q = qw + qt * 32 + l32;
                unsafeAtomicAdd(&out[((size_t)t * F + f) * (size_t)N + q], oacc[ft][qt][r]);
            }
}

// ---------------------------------------------------------------------------
extern "C" void kernel_launch(void* const* d_in, const int* in_sizes, int n_in,
                              void* d_out, int out_size, void* d_ws, size_t ws_size,
                              hipStream_t stream) {
    const float* x1 = (const float*)d_in[0];
    const float* x2 = (const float*)d_in[1];
    const float* W1 = (const float*)d_in[2];
    const float* b1 = (const float*)d_in[3];
    const float* W2 = (const float*)d_in[4];
    const float* b2 = (const float*)d_in[5];
    const float* W3 = (const float*)d_in[6];
    const float* b3 = (const float*)d_in[7];
    float* out = (float*)d_out;

    // workspace: Q [t][n][F], K [t][n][F], G [t][f][N] bf16 (3 x 4 MiB)
    __bf16* Qb = (__bf16*)d_ws;
    __bf16* Kb = Qb + (size_t)T * N * F;
    __bf16* Gw = Kb + (size_t)T * N * F;

    proj_kernel<<<dim3(T * (N / 64)), dim3(256), 0, stream>>>(
        x1, x2, W1, b1, W2, b2, W3, b3, Qb, Kb, Gw, out);
    attn_kernel<<<dim3(T * 16 * KSPLIT), dim3(256), 0, stream>>>(Qb, Kb, Gw, out);
}

// Round 7
// 173.690 us; speedup vs baseline: 1.1870x; 1.0558x over previous
//
#include <hip/hip_runtime.h>
#include <hip/hip_bf16.h>

// Problem constants (B=1 folded out)
constexpr int T = 8;     // frames
constexpr int C = 128;   // input channels
constexpr int N = 4096;  // H*W positions
constexpr int F = 64;    // feature dim

typedef __bf16 bf16x8 __attribute__((ext_vector_type(8)));
typedef __bf16 bf16x4 __attribute__((ext_vector_type(4)));
typedef float  f32x4  __attribute__((ext_vector_type(4)));
typedef float  f32x16 __attribute__((ext_vector_type(16)));

// ---------------------------------------------------------------------------
// Kernel 1: projections, LDS-free (unchanged — known correct).
//   Q = x1ᵀW1ᵀ+b1  -> bf16 [t][n][F]
//   K = x2ᵀW2ᵀ+b2  -> bf16 [t][n][F]
//   G = x1ᵀW3ᵀ+b3  -> bf16 [t][f][N]
// Also zeroes d_out (poisoned 0xAA; attn accumulates atomically).
// ---------------------------------------------------------------------------
__global__ __launch_bounds__(256) void proj_kernel(
    const float* __restrict__ x1, const float* __restrict__ x2,
    const float* __restrict__ W1, const float* __restrict__ b1,
    const float* __restrict__ W2, const float* __restrict__ b2,
    const float* __restrict__ W3, const float* __restrict__ b3,
    __bf16* __restrict__ Qb, __bf16* __restrict__ Kb, __bf16* __restrict__ Gw,
    float* __restrict__ out)
{
    const int t   = blockIdx.x >> 6;    // 64 blocks per t, 64 npos per block
    const int nb  = blockIdx.x & 63;
    const int tid = threadIdx.x, wave = tid >> 6, lane = tid & 63;
    const int quad = lane >> 4, l16 = lane & 15;
    const int nw = nb * 64 + wave * 16;          // this wave's 16 positions

    // zero this block's 4096-float slice of d_out (512 blocks cover T*F*N)
    {
        f32x4* o4 = (f32x4*)out + (size_t)blockIdx.x * 1024;
#pragma unroll
        for (int i = 0; i < 4; ++i) o4[i * 256 + tid] = (f32x4){0.f, 0.f, 0.f, 0.f};
    }

    // x B-frags: B[k=c][n'=npos]; lane n'=l16, k = cc*32 + quad*8 + j
    bf16x8 xf1[4], xf2[4];
#pragma unroll
    for (int cc = 0; cc < 4; ++cc) {
#pragma unroll
        for (int j = 0; j < 8; ++j) {
            size_t off = ((size_t)t * C + cc * 32 + quad * 8 + j) * (size_t)N + nw + l16;
            xf1[cc][j] = (__bf16)x1[off];
            xf2[cc][j] = (__bf16)x2[off];
        }
    }

    const float* Ws[3] = {W1, W2, W3};
    const float* bs[3] = {b1, b2, b3};

#pragma unroll
    for (int p = 0; p < 3; ++p) {
        const float* W    = Ws[p];
        const float* bias = bs[p];
#pragma unroll
        for (int fb = 0; fb < 4; ++fb) {
            f32x4 acc = (f32x4){0.f, 0.f, 0.f, 0.f};
#pragma unroll
            for (int cc = 0; cc < 4; ++cc) {
                const f32x4* wp = (const f32x4*)&W[(fb * 16 + l16) * C + cc * 32 + quad * 8];
                f32x4 w0 = wp[0], w1 = wp[1];
                bf16x8 wf;
                wf[0] = (__bf16)w0[0]; wf[1] = (__bf16)w0[1];
                wf[2] = (__bf16)w0[2]; wf[3] = (__bf16)w0[3];
                wf[4] = (__bf16)w1[0]; wf[5] = (__bf16)w1[1];
                wf[6] = (__bf16)w1[2]; wf[7] = (__bf16)w1[3];
                bf16x8 xb = (p == 1) ? xf2[cc] : xf1[cc];
                acc = __builtin_amdgcn_mfma_f32_16x16x32_bf16(wf, xb, acc, 0, 0, 0);
            }
            if (p < 2) {
                __bf16* O = p ? Kb : Qb;
                bf16x4 ov;
#pragma unroll
                for (int r = 0; r < 4; ++r)
                    ov[r] = (__bf16)(acc[r] + bias[fb * 16 + quad * 4 + r]);
                *(bf16x4*)&O[((size_t)t * N + nw + l16) * F + fb * 16 + quad * 4] = ov;
            } else {
#pragma unroll
                for (int r = 0; r < 4; ++r) {
                    int f = fb * 16 + quad * 4 + r;
                    Gw[((size_t)t * F + f) * (size_t)N + nw + l16] = (__bf16)(acc[r] + bias[f]);
                }
            }
        }
    }
}

// ---------------------------------------------------------------------------
// pack two relu'd fp32 into a bf16x2 dword
// ---------------------------------------------------------------------------
__device__ inline unsigned pk_relu(float a, float b) {
    union { __bf16 h[2]; unsigned u; } x;
    x.h[0] = (__bf16)fmaxf(a, 0.f);
    x.h[1] = (__bf16)fmaxf(b, 0.f);
    return x.u;
}

// ---------------------------------------------------------------------------
// Kernel 2: O[t][f][q] += sum_key relu(Q[q]·K[key]) * G[key][f]
// mfma_f32_32x32x16_bf16, R5/R6-proven layouts. SOFTWARE-PIPELINED:
//   iter i: [stage K(i) LDS dbuf][prefetch K(i+1) regs][barrier]
//           [PV(i-1) via reg G-frags][load G-frags(i)][S(i)+transform]
// -> PV and S chains independent per iter; G-frag global loads get a full
// iteration of latency cover; ONE barrier per 64-key tile (dbuf: writes to
// buf p at iter i are barrier-separated from buf-p reads at iter i-2).
// LDS = 16 KB (K dbuf only, XOR-swizzled). Wave owns 64 q; block = 256 q.
// KSPLIT=4; fp32 atomic accumulate into out[t][f][n].
// ---------------------------------------------------------------------------
constexpr int KSPLIT = 4;
constexpr int NTILES = N / 64 / KSPLIT;   // 16

__global__ __launch_bounds__(256, 2) void attn_kernel(
    const __bf16* __restrict__ Qb, const __bf16* __restrict__ Kb,
    const __bf16* __restrict__ Gw, float* __restrict__ out)
{
    const int ks = blockIdx.x & (KSPLIT - 1);
    const int qb = (blockIdx.x / KSPLIT) & 15;   // N/256 = 16 q-blocks
    const int t  = blockIdx.x / (KSPLIT * 16);

    __shared__ __bf16 Kt[2][64 * 64];   // [key][f], 16B chunks XOR-swizzled, dbuf

    const int tid = threadIdx.x, wave = tid >> 6, lane = tid & 63;
    const int l32 = lane & 31, h = lane >> 5;
    const int qw = qb * 256 + wave * 64;         // this wave's 64 queries

    const __bf16* Kbase = Kb + (size_t)t * N * F;
    const __bf16* Gbase = Gw + (size_t)t * F * N;

    // persistent Q B-frags: B[n=q][k=f]; q = qw + qt*32 + l32, f = c*16 + h*8 + j
    bf16x8 qf[2][4];
#pragma unroll
    for (int qt = 0; qt < 2; ++qt)
#pragma unroll
        for (int c = 0; c < 4; ++c)
            qf[qt][c] = *(const bf16x8*)&Qb[((size_t)t * N + qw + qt * 32 + l32) * F + c * 16 + h * 8];

    f32x16 oacc[2][2];   // [ft][qt], Oᵀ subtiles: col=q, row=f
#pragma unroll
    for (int ft = 0; ft < 2; ++ft)
#pragma unroll
        for (int qt = 0; qt < 2; ++qt)
#pragma unroll
            for (int i = 0; i < 16; ++i) oacc[ft][qt][i] = 0.f;

    const int kb_lo = ks * NTILES;

    // staging: 2 units/thread; row = unit>>3, chunk = unit&7, XOR-swizzled
    const int ra = tid >> 3, ca = tid & 7;       // rows 0..31
    const int rb = ra + 32,  cb = ca;            // rows 32..63
    const int wKa = ra * 64 + ((ca ^ (ra & 7)) * 8);
    const int wKb = rb * 64 + ((cb ^ (rb & 7)) * 8);

    bf16x8 kv0, kv1;       // K staging regs
    bf16x8 gf[2][4];       // G PV A-frags (global, reg-resident)
    bf16x8 sfrag[2][4];    // S PV B-frags

    // ---- prolog: tile 0 ----
    {
        const int k0 = kb_lo * 64;
        kv0 = *(const bf16x8*)&Kbase[(size_t)(k0 + ra) * F + ca * 8];
        kv1 = *(const bf16x8*)&Kbase[(size_t)(k0 + rb) * F + cb * 8];
        *(bf16x8*)&Kt[0][wKa] = kv0;
        *(bf16x8*)&Kt[0][wKb] = kv1;
        // G-frags for tile 0: A[m=f][k=key], m = ft*32+l32, k = kc*16+h*8+j
#pragma unroll
        for (int ft = 0; ft < 2; ++ft)
#pragma unroll
            for (int kc = 0; kc < 4; ++kc)
                gf[ft][kc] = *(const bf16x8*)&Gbase[(size_t)(ft * 32 + l32) * N + k0 + kc * 16 + h * 8];
        // prefetch tile 1
        const int k1 = k0 + 64;
        kv0 = *(const bf16x8*)&Kbase[(size_t)(k1 + ra) * F + ca * 8];
        kv1 = *(const bf16x8*)&Kbase[(size_t)(k1 + rb) * F + cb * 8];
    }
    __syncthreads();

    // ---- S(0) + transform -> sfrag ----
#pragma unroll
    for (int kt = 0; kt < 2; ++kt) {
        f32x16 sd[2];
#pragma unroll
        for (int qt = 0; qt < 2; ++qt)
#pragma unroll
            for (int i = 0; i < 16; ++i) sd[qt][i] = 0.f;
#pragma unroll
        for (int c = 0; c < 4; ++c) {
            int row = kt * 32 + l32;
            bf16x8 kf = *(const bf16x8*)&Kt[0][row * 64 + (((2 * c + h) ^ (row & 7)) * 8)];
            sd[0] = __builtin_amdgcn_mfma_f32_32x32x16_bf16(kf, qf[0][c], sd[0], 0, 0, 0);
            sd[1] = __builtin_amdgcn_mfma_f32_32x32x16_bf16(kf, qf[1][c], sd[1], 0, 0, 0);
        }
#pragma unroll
        for (int qt = 0; qt < 2; ++qt) {
            unsigned p0 = pk_relu(sd[qt][0],  sd[qt][1]);
            unsigned p1 = pk_relu(sd[qt][2],  sd[qt][3]);
            unsigned p2 = pk_relu(sd[qt][4],  sd[qt][5]);
            unsigned p3 = pk_relu(sd[qt][6],  sd[qt][7]);
            unsigned p4 = pk_relu(sd[qt][8],  sd[qt][9]);
            unsigned p5 = pk_relu(sd[qt][10], sd[qt][11]);
            unsigned p6 = pk_relu(sd[qt][12], sd[qt][13]);
            unsigned p7 = pk_relu(sd[qt][14], sd[qt][15]);
            unsigned r0 = (unsigned)__shfl_xor((int)(h ? p0 : p2), 32, 64);
            unsigned r1 = (unsigned)__shfl_xor((int)(h ? p1 : p3), 32, 64);
            unsigned r2 = (unsigned)__shfl_xor((int)(h ? p4 : p6), 32, 64);
            unsigned r3 = (unsigned)__shfl_xor((int)(h ? p5 : p7), 32, 64);
            union { unsigned u[4]; bf16x8 v; } f0, f1;
            f0.u[0] = h ? r0 : p0;  f0.u[1] = h ? r1 : p1;
            f0.u[2] = h ? p2 : r0;  f0.u[3] = h ? p3 : r1;
            f1.u[0] = h ? r2 : p4;  f1.u[1] = h ? r3 : p5;
            f1.u[2] = h ? p6 : r2;  f1.u[3] = h ? p7 : r3;
            sfrag[qt][kt * 2 + 0] = f0.v;
            sfrag[qt][kt * 2 + 1] = f1.v;
        }
    }

    // ---- pipelined main loop: tiles 1..NTILES-1 ----
    for (int i = 1; i < NTILES; ++i) {
        const int p = i & 1;
        // stage tile i (in staging regs) into buf p
        *(bf16x8*)&Kt[p][wKa] = kv0;
        *(bf16x8*)&Kt[p][wKb] = kv1;
        // prefetch tile i+1 into staging regs
        if (i + 1 < NTILES) {
            const int kn = (kb_lo + i + 1) * 64;
            kv0 = *(const bf16x8*)&Kbase[(size_t)(kn + ra) * F + ca * 8];
            kv1 = *(const bf16x8*)&Kbase[(size_t)(kn + rb) * F + cb * 8];
        }
        __syncthreads();

        // PV(i-1): oacc += gf x sfrag   (independent of S(i) below)
#pragma unroll
        for (int ft = 0; ft < 2; ++ft)
#pragma unroll
            for (int kc = 0; kc < 4; ++kc) {
                oacc[ft][0] = __builtin_amdgcn_mfma_f32_32x32x16_bf16(gf[ft][kc], sfrag[0][kc], oacc[ft][0], 0, 0, 0);
                oacc[ft][1] = __builtin_amdgcn_mfma_f32_32x32x16_bf16(gf[ft][kc], sfrag[1][kc], oacc[ft][1], 0, 0, 0);
            }

        const int k0 = (kb_lo + i) * 64;
        // load G-frags for tile i (consumed by PV(i) next iter -> latency hidden)
#pragma unroll
        for (int ft = 0; ft < 2; ++ft)
#pragma unroll
            for (int kc = 0; kc < 4; ++kc)
                gf[ft][kc] = *(const bf16x8*)&Gbase[(size_t)(ft * 32 + l32) * N + k0 + kc * 16 + h * 8];

        // S(i) from Kt[p] + transform -> sfrag
#pragma unroll
        for (int kt = 0; kt < 2; ++kt) {
            f32x16 sd[2];
#pragma unroll
            for (int qt = 0; qt < 2; ++qt)
#pragma unroll
                for (int j = 0; j < 16; ++j) sd[qt][j] = 0.f;
#pragma unroll
            for (int c = 0; c < 4; ++c) {
                int row = kt * 32 + l32;
                bf16x8 kf = *(const bf16x8*)&Kt[p][row * 64 + (((2 * c + h) ^ (row & 7)) * 8)];
                sd[0] = __builtin_amdgcn_mfma_f32_32x32x16_bf16(kf, qf[0][c], sd[0], 0, 0, 0);
                sd[1] = __builtin_amdgcn_mfma_f32_32x32x16_bf16(kf, qf[1][c], sd[1], 0, 0, 0);
            }
#pragma unroll
            for (int qt = 0; qt < 2; ++qt) {
                unsigned p0 = pk_relu(sd[qt][0],  sd[qt][1]);
                unsigned p1 = pk_relu(sd[qt][2],  sd[qt][3]);
                unsigned p2 = pk_relu(sd[qt][4],  sd[qt][5]);
                unsigned p3 = pk_relu(sd[qt][6],  sd[qt][7]);
                unsigned p4 = pk_relu(sd[qt][8],  sd[qt][9]);
                unsigned p5 = pk_relu(sd[qt][10], sd[qt][11]);
                unsigned p6 = pk_relu(sd[qt][12], sd[qt][13]);
                unsigned p7 = pk_relu(sd[qt][14], sd[qt][15]);
                unsigned r0 = (unsigned)__shfl_xor((int)(h ? p0 : p2), 32, 64);
                unsigned r1 = (unsigned)__shfl_xor((int)(h ? p1 : p3), 32, 64);
                unsigned r2 = (unsigned)__shfl_xor((int)(h ? p4 : p6), 32, 64);
                unsigned r3 = (unsigned)__shfl_xor((int)(h ? p5 : p7), 32, 64);
                union { unsigned u[4]; bf16x8 v; } f0, f1;
                f0.u[0] = h ? r0 : p0;  f0.u[1] = h ? r1 : p1;
                f0.u[2] = h ? p2 : r0;  f0.u[3] = h ? p3 : r1;
                f1.u[0] = h ? r2 : p4;  f1.u[1] = h ? r3 : p5;
                f1.u[2] = h ? p6 : r2;  f1.u[3] = h ? p7 : r3;
                sfrag[qt][kt * 2 + 0] = f0.v;
                sfrag[qt][kt * 2 + 1] = f1.v;
            }
        }
    }

    // ---- epilog: PV(NTILES-1) ----
#pragma unroll
    for (int ft = 0; ft < 2; ++ft)
#pragma unroll
        for (int kc = 0; kc < 4; ++kc) {
            oacc[ft][0] = __builtin_amdgcn_mfma_f32_32x32x16_bf16(gf[ft][kc], sfrag[0][kc], oacc[ft][0], 0, 0, 0);
            oacc[ft][1] = __builtin_amdgcn_mfma_f32_32x32x16_bf16(gf[ft][kc], sfrag[1][kc], oacc[ft][1], 0, 0, 0);
        }

    // Epilogue: D col = q = l32, row = f_local = (r&3) + 8*(r>>2) + 4*h
#pragma unroll
    for (int ft = 0; ft < 2; ++ft)
#pragma unroll
        for (int qt = 0; qt < 2; ++qt)
#pragma unroll
            for (int r = 0; r < 16; ++r) {
                int f = ft * 32 + (r & 3) + 8 * (r >> 2) + 4 * h;
                int q = qw + qt * 32 + l32;
                unsafeAtomicAdd(&out[((size_t)t * F + f) * (size_t)N + q], oacc[ft][qt][r]);
            }
}

// ---------------------------------------------------------------------------
extern "C" void kernel_launch(void* const* d_in, const int* in_sizes, int n_in,
                              void* d_out, int out_size, void* d_ws, size_t ws_size,
                              hipStream_t stream) {
    const float* x1 = (const float*)d_in[0];
    const float* x2 = (const float*)d_in[1];
    const float* W1 = (const float*)d_in[2];
    const float* b1 = (const float*)d_in[3];
    const float* W2 = (const float*)d_in[4];
    const float* b2 = (const float*)d_in[5];
    const float* W3 = (const float*)d_in[6];
    const float* b3 = (const float*)d_in[7];
    float* out = (float*)d_out;

    // workspace: Q [t][n][F], K [t][n][F], G [t][f][N] bf16 (3 x 4 MiB)
    __bf16* Qb = (__bf16*)d_ws;
    __bf16* Kb = Qb + (size_t)T * N * F;
    __bf16* Gw = Kb + (size_t)T * N * F;

    proj_kernel<<<dim3(T * (N / 64)), dim3(256), 0, stream>>>(
        x1, x2, W1, b1, W2, b2, W3, b3, Qb, Kb, Gw, out);
    attn_kernel<<<dim3(T * 16 * KSPLIT), dim3(256), 0, stream>>>(Qb, Kb, Gw, out);
}